// Round 5
// baseline (560.176 us; speedup 1.0000x reference)
//
#include <hip/hip_runtime.h>
#include <hip/hip_bf16.h>

// Problem constants (match reference)
#define NN 100000     // nodes
#define NE 1600000    // edges
#define HD 128        // feature/hidden dim
#define NG 512        // graphs
#define BN_EPS 1e-5f

typedef __attribute__((ext_vector_type(8))) short short8;
typedef __attribute__((ext_vector_type(4))) float floatx4;

// ---- bf16 helpers (RNE) ----
__device__ __forceinline__ ushort f2bf(float f) {
    union { float f; uint u; } v; v.f = f;
    uint r = (v.u + 0x7FFF + ((v.u >> 16) & 1)) >> 16;
    return (ushort)r;
}
__device__ __forceinline__ float bflo(uint u) { union { uint u; float f; } v; v.u = u << 16; return v.f; }
__device__ __forceinline__ float bfhi(uint u) { union { uint u; float f; } v; v.u = u & 0xFFFF0000u; return v.f; }

// ---------------- zero helper ----------------
__global__ void k_zero_i(int* p, int n) {
    int i = blockIdx.x * 256 + threadIdx.x;
    if (i < n) p[i] = 0;
}

// ---------------- degree histogram + per-edge rank (ONE atomic pass) ----------------
__global__ void k_hist_rank(const int* __restrict__ dst, int* __restrict__ indeg,
                            int* __restrict__ rank) {
    int e = blockIdx.x * 256 + threadIdx.x;
    if (e < NE) rank[e] = atomicAdd(&indeg[dst[e]], 1);
}

__global__ void k_dinv(const int* __restrict__ indeg, float* __restrict__ dinv) {
    int i = blockIdx.x * 256 + threadIdx.x;
    if (i < NN) dinv[i] = rsqrtf((float)(indeg[i] + 1));
}

// ---------------- hierarchical exclusive scan ----------------
__global__ void k_scan1(const int* __restrict__ indeg, int* __restrict__ rs, int* __restrict__ aux) {
    __shared__ int s[256];
    int t = threadIdx.x;
    int base = blockIdx.x * 1024 + t * 4;
    int v0 = 0, v1 = 0, v2 = 0, v3 = 0;
    if (base + 0 < NN) v0 = indeg[base + 0];
    if (base + 1 < NN) v1 = indeg[base + 1];
    if (base + 2 < NN) v2 = indeg[base + 2];
    if (base + 3 < NN) v3 = indeg[base + 3];
    int tsum = v0 + v1 + v2 + v3;
    s[t] = tsum;
    __syncthreads();
    for (int o = 1; o < 256; o <<= 1) {
        int x = 0;
        if (t >= o) x = s[t - o];
        __syncthreads();
        s[t] += x;
        __syncthreads();
    }
    int excl = s[t] - tsum;
    if (base + 0 < NN) rs[base + 0] = excl;
    if (base + 1 < NN) rs[base + 1] = excl + v0;
    if (base + 2 < NN) rs[base + 2] = excl + v0 + v1;
    if (base + 3 < NN) rs[base + 3] = excl + v0 + v1 + v2;
    if (t == 255) aux[blockIdx.x] = s[255];
}

__global__ void k_scan2(int* __restrict__ aux, int nblk) {
    __shared__ int s[128];
    int t = threadIdx.x;
    int v = (t < nblk) ? aux[t] : 0;
    s[t] = v;
    __syncthreads();
    for (int o = 1; o < 128; o <<= 1) {
        int x = 0;
        if (t >= o) x = s[t - o];
        __syncthreads();
        s[t] += x;
        __syncthreads();
    }
    if (t < nblk) aux[t] = s[t] - v;
}

__global__ void k_scan3(int* __restrict__ rs, const int* __restrict__ aux) {
    int i = blockIdx.x * 256 + threadIdx.x;
    if (i < NN) rs[i] += aux[i >> 10];
    if (i == 0) rs[NN] = NE;
}

// ---------------- CSR fill (atomic-free) ----------------
__global__ void k_fill(const int* __restrict__ src, const int* __restrict__ dst,
                       const int* __restrict__ rank, const int* __restrict__ rs,
                       int* __restrict__ csr) {
    int e = blockIdx.x * 256 + threadIdx.x;
    if (e >= NE) return;
    csr[rs[dst[e]] + rank[e]] = src[e];
}

// ---------------- BN affine prep ----------------
__global__ void k_bn_prep(const float* __restrict__ b, const float* __restrict__ g,
                          const float* __restrict__ be, const float* __restrict__ m,
                          const float* __restrict__ v, float* scale, float* shift) {
    int f = threadIdx.x;
    if (f < HD) {
        float sc = g[f] * rsqrtf(v[f] + BN_EPS);
        scale[f] = sc;
        shift[f] = (b[f] - m[f]) * sc + be[f];
    }
}

// ---------------- graph boundaries ----------------
__global__ void k_gstart(const int* __restrict__ batch, int* __restrict__ gstart) {
    int g = blockIdx.x * 256 + threadIdx.x;
    if (g > NG) return;
    if (g == NG) { gstart[NG] = NN; return; }
    int lo = 0, hi = NN;
    while (lo < hi) {
        int mid = (lo + hi) >> 1;
        if (batch[mid] < g) lo = mid + 1; else hi = mid;
    }
    gstart[g] = lo;
}

// ---------------- W prep: Wt[n][k] = bf16(W[k][n]) ----------------
__global__ void k_prep_w(const float* __restrict__ W, ushort* __restrict__ Wt) {
    int i = blockIdx.x * 256 + threadIdx.x;
    if (i < 128 * 128) {
        int k = i >> 7, n = i & 127;
        Wt[n * 128 + k] = f2bf(W[i]);
    }
}

// ---------------- MFMA GEMM (LDS-free B, coalesced epilogue) ----------------
// hs = bf16( (x @ W) * dinv[row] ).  256 thr = 4 waves; block covers 64 rows.
// Wt is bf16 [n][k] in global (32 KB, L1-resident). F32 selects fp32 input (layer 1).
template <bool F32>
__launch_bounds__(256)
__global__ void k_gemm(const void* __restrict__ xin, const ushort* __restrict__ Wt,
                       const float* __restrict__ dinv, ushort* __restrict__ hs) {
    __shared__ ushort sEp[64 * 128];     // 16 KB epilogue staging
    const int tid = threadIdx.x;
    const int wave = tid >> 6, lane = tid & 63;
    const int m = lane & 15, kg = lane >> 4;
    const long rowB = (long)blockIdx.x * 64;
    const long row0 = rowB + wave * 16;

    long arow = row0 + m;
    long arc = arow < NN ? arow : (NN - 1);
    short8 a[4];
    if (F32) {
        const float* xf = (const float*)xin + arc * 128;
#pragma unroll
        for (int s = 0; s < 4; ++s) {
            float4 f0 = *(const float4*)(xf + s * 32 + kg * 8);
            float4 f1 = *(const float4*)(xf + s * 32 + kg * 8 + 4);
            short8 t;
            t[0] = (short)f2bf(f0.x); t[1] = (short)f2bf(f0.y);
            t[2] = (short)f2bf(f0.z); t[3] = (short)f2bf(f0.w);
            t[4] = (short)f2bf(f1.x); t[5] = (short)f2bf(f1.y);
            t[6] = (short)f2bf(f1.z); t[7] = (short)f2bf(f1.w);
            a[s] = t;
        }
    } else {
        const ushort* xb = (const ushort*)xin + arc * 128;
#pragma unroll
        for (int s = 0; s < 4; ++s)
            a[s] = *(const short8*)(xb + s * 32 + kg * 8);
    }

    floatx4 acc[8];
#pragma unroll
    for (int ct = 0; ct < 8; ++ct) acc[ct] = (floatx4){0.f, 0.f, 0.f, 0.f};

#pragma unroll
    for (int s = 0; s < 4; ++s) {
#pragma unroll
        for (int ct = 0; ct < 8; ++ct) {
            short8 b = *(const short8*)(Wt + (ct * 16 + m) * 128 + s * 32 + kg * 8);
            acc[ct] = __builtin_amdgcn_mfma_f32_16x16x32_bf16(a[s], b, acc[ct], 0, 0, 0);
        }
    }

    // epilogue: scale rows by dinv, stage bf16 into LDS
#pragma unroll
    for (int r = 0; r < 4; ++r) {
        long orow = row0 + kg * 4 + r;
        long orc = orow < NN ? orow : (NN - 1);
        float dd = dinv[orc];
#pragma unroll
        for (int ct = 0; ct < 8; ++ct)
            sEp[(wave * 16 + kg * 4 + r) * 128 + ct * 16 + m] = f2bf(acc[ct][r] * dd);
    }
    __syncthreads();

    // coalesced write-back: 1024 uint4 total, 4 per thread
#pragma unroll
    for (int it = 0; it < 4; ++it) {
        int idx = it * 256 + tid;
        int row = idx >> 4;
        int col = (idx & 15) * 8;
        long grow = rowB + row;
        if (grow < NN)
            *(uint4*)(hs + grow * 128 + col) = *(const uint4*)&sEp[row * 128 + col];
    }
}

// ---------------- gather + BN + ReLU fused: 16 lanes/node, uint4 loads, 4x unroll ----------------
__global__ void k_gather_bf(const ushort* __restrict__ hs, const int* __restrict__ rs,
                            const int* __restrict__ csr, const float* __restrict__ dinv,
                            const float* __restrict__ scale, const float* __restrict__ shift,
                            ushort* __restrict__ xout) {
    int t = blockIdx.x * 256 + threadIdx.x;
    int d = t >> 4;
    if (d >= NN) return;
    int lane = t & 15;
    int c0 = lane * 8;
    int e0 = rs[d], e1 = rs[d + 1];

    uint4 sv = *(const uint4*)(hs + (long)d * 128 + c0);   // self-loop term
    float a0 = bflo(sv.x), a1 = bfhi(sv.x), a2 = bflo(sv.y), a3 = bfhi(sv.y);
    float a4 = bflo(sv.z), a5 = bfhi(sv.z), a6 = bflo(sv.w), a7 = bfhi(sv.w);

    int j = e0;
    for (; j + 3 < e1; j += 4) {
        int s0 = csr[j], s1 = csr[j + 1], s2 = csr[j + 2], s3 = csr[j + 3];
        uint4 v0 = *(const uint4*)(hs + (long)s0 * 128 + c0);
        uint4 v1 = *(const uint4*)(hs + (long)s1 * 128 + c0);
        uint4 v2 = *(const uint4*)(hs + (long)s2 * 128 + c0);
        uint4 v3 = *(const uint4*)(hs + (long)s3 * 128 + c0);
        a0 += (bflo(v0.x) + bflo(v1.x)) + (bflo(v2.x) + bflo(v3.x));
        a1 += (bfhi(v0.x) + bfhi(v1.x)) + (bfhi(v2.x) + bfhi(v3.x));
        a2 += (bflo(v0.y) + bflo(v1.y)) + (bflo(v2.y) + bflo(v3.y));
        a3 += (bfhi(v0.y) + bfhi(v1.y)) + (bfhi(v2.y) + bfhi(v3.y));
        a4 += (bflo(v0.z) + bflo(v1.z)) + (bflo(v2.z) + bflo(v3.z));
        a5 += (bfhi(v0.z) + bfhi(v1.z)) + (bfhi(v2.z) + bfhi(v3.z));
        a6 += (bflo(v0.w) + bflo(v1.w)) + (bflo(v2.w) + bflo(v3.w));
        a7 += (bfhi(v0.w) + bfhi(v1.w)) + (bfhi(v2.w) + bfhi(v3.w));
    }
    for (; j < e1; ++j) {
        int s0 = csr[j];
        uint4 v0 = *(const uint4*)(hs + (long)s0 * 128 + c0);
        a0 += bflo(v0.x); a1 += bfhi(v0.x);
        a2 += bflo(v0.y); a3 += bfhi(v0.y);
        a4 += bflo(v0.z); a5 += bfhi(v0.z);
        a6 += bflo(v0.w); a7 += bfhi(v0.w);
    }

    float dd = dinv[d];
    float4 sca = *(const float4*)(scale + c0);
    float4 scb = *(const float4*)(scale + c0 + 4);
    float4 sha = *(const float4*)(shift + c0);
    float4 shb = *(const float4*)(shift + c0 + 4);
    float r0 = fmaxf(dd * a0 * sca.x + sha.x, 0.f);
    float r1 = fmaxf(dd * a1 * sca.y + sha.y, 0.f);
    float r2 = fmaxf(dd * a2 * sca.z + sha.z, 0.f);
    float r3 = fmaxf(dd * a3 * sca.w + sha.w, 0.f);
    float r4 = fmaxf(dd * a4 * scb.x + shb.x, 0.f);
    float r5 = fmaxf(dd * a5 * scb.y + shb.y, 0.f);
    float r6 = fmaxf(dd * a6 * scb.z + shb.z, 0.f);
    float r7 = fmaxf(dd * a7 * scb.w + shb.w, 0.f);
    uint4 o;
    o.x = (uint)f2bf(r0) | ((uint)f2bf(r1) << 16);
    o.y = (uint)f2bf(r2) | ((uint)f2bf(r3) << 16);
    o.z = (uint)f2bf(r4) | ((uint)f2bf(r5) << 16);
    o.w = (uint)f2bf(r6) | ((uint)f2bf(r7) << 16);
    *(uint4*)(xout + (long)d * 128 + c0) = o;
}

// ---------------- fused mean-pool + final linear (bf16 input) ----------------
__global__ void k_pool_final2(const ushort* __restrict__ x, const int* __restrict__ gstart,
                              const float* __restrict__ Wl, const float* __restrict__ bl,
                              float* __restrict__ out) {
    __shared__ float red[256];
    int g = blockIdx.x;
    int tid = threadIdx.x;
    int f = tid & 127;
    int half = tid >> 7;
    int i0 = gstart[g], i1 = gstart[g + 1];

    float acc = 0.f;
    for (int i = i0 + half; i < i1; i += 2) {
        union { uint u; float f; } v; v.u = (uint)x[(long)i * 128 + f] << 16;
        acc += v.f;
    }
    red[tid] = acc;
    __syncthreads();
    if (tid < 128) red[tid] = (red[tid] + red[tid + 128]) * Wl[tid];
    __syncthreads();
    for (int o = 64; o > 0; o >>= 1) {
        if (tid < o) red[tid] += red[tid + o];
        __syncthreads();
    }
    if (tid == 0) out[g] = red[0] / fmaxf((float)(i1 - i0), 1.f) + bl[0];
}

// ---------------- launch ----------------
extern "C" void kernel_launch(void* const* d_in, const int* in_sizes, int n_in,
                              void* d_out, int out_size, void* d_ws, size_t ws_size,
                              hipStream_t stream) {
    const float* x   = (const float*)d_in[0];
    const int*   ei  = (const int*)d_in[1];
    const int*   bat = (const int*)d_in[2];
    const float* W1  = (const float*)d_in[3];
    const float* b1  = (const float*)d_in[4];
    const float* g1  = (const float*)d_in[5];
    const float* be1 = (const float*)d_in[6];
    const float* m1  = (const float*)d_in[7];
    const float* v1  = (const float*)d_in[8];
    const float* W2  = (const float*)d_in[9];
    const float* b2  = (const float*)d_in[10];
    const float* g2  = (const float*)d_in[11];
    const float* be2 = (const float*)d_in[12];
    const float* m2  = (const float*)d_in[13];
    const float* v2  = (const float*)d_in[14];
    const float* W3  = (const float*)d_in[15];
    const float* b3  = (const float*)d_in[16];
    const float* g3  = (const float*)d_in[17];
    const float* be3 = (const float*)d_in[18];
    const float* m3  = (const float*)d_in[19];
    const float* v3  = (const float*)d_in[20];
    const float* Wl  = (const float*)d_in[21];
    const float* bl  = (const float*)d_in[22];
    float* out = (float*)d_out;

    const int* srcp = ei;        // edge_index[0]
    const int* dstp = ei + NE;   // edge_index[1]

    // ---- workspace layout ----
    char* ws = (char*)d_ws;
    size_t off = 0;
    auto alloc = [&](size_t bytes) { char* p = ws + off; off += (bytes + 255) & ~255ULL; return p; };
    float*  dinv   = (float*) alloc(NN * 4);
    int*    indeg  = (int*)   alloc(NN * 4);
    int*    rs     = (int*)   alloc((NN + 1) * 4);
    int*    aux    = (int*)   alloc(128 * 4);
    int*    csr    = (int*)   alloc(NE * 4);           // 6.4 MB
    int*    rank   = (int*)   alloc(NE * 4);           // 6.4 MB
    float*  scale1 = (float*) alloc(HD * 4);
    float*  shift1 = (float*) alloc(HD * 4);
    float*  scale2 = (float*) alloc(HD * 4);
    float*  shift2 = (float*) alloc(HD * 4);
    float*  scale3 = (float*) alloc(HD * 4);
    float*  shift3 = (float*) alloc(HD * 4);
    int*    gstart = (int*)   alloc((NG + 1) * 4);
    ushort* Wt1    = (ushort*)alloc(128 * 128 * 2);    // 32 KB
    ushort* Wt2    = (ushort*)alloc(128 * 128 * 2);
    ushort* Wt3    = (ushort*)alloc(128 * 128 * 2);
    ushort* hs     = (ushort*)alloc((size_t)NN * HD * 2);   // 25.6 MB
    ushort* xbuf   = (ushort*)alloc((size_t)NN * HD * 2);   // 25.6 MB

    const int nblk_scan = (NN + 1023) / 1024;
    const int grid_n    = (NN + 255) / 256;
    const int grid_e    = (NE + 255) / 256;
    const int gemm_grid = (NN + 63) / 64;                   // 1563
    const int gath_grid = (NN * 16 + 255) / 256;            // 6250
    const int prep_grid = (128 * 128 + 255) / 256;          // 64

    // ---- CSR build: one atomic pass (hist+rank), then atomic-free fill ----
    k_zero_i<<<grid_n, 256, 0, stream>>>(indeg, NN);
    k_hist_rank<<<grid_e, 256, 0, stream>>>(dstp, indeg, rank);
    k_dinv<<<grid_n, 256, 0, stream>>>(indeg, dinv);
    k_scan1<<<nblk_scan, 256, 0, stream>>>(indeg, rs, aux);
    k_scan2<<<1, 128, 0, stream>>>(aux, nblk_scan);
    k_scan3<<<grid_n, 256, 0, stream>>>(rs, aux);
    k_fill<<<grid_e, 256, 0, stream>>>(srcp, dstp, rank, rs, csr);

    // ---- BN prep + graph boundaries + W transposes ----
    k_bn_prep<<<1, 128, 0, stream>>>(b1, g1, be1, m1, v1, scale1, shift1);
    k_bn_prep<<<1, 128, 0, stream>>>(b2, g2, be2, m2, v2, scale2, shift2);
    k_bn_prep<<<1, 128, 0, stream>>>(b3, g3, be3, m3, v3, scale3, shift3);
    k_gstart<<<3, 256, 0, stream>>>(bat, gstart);
    k_prep_w<<<prep_grid, 256, 0, stream>>>(W1, Wt1);
    k_prep_w<<<prep_grid, 256, 0, stream>>>(W2, Wt2);
    k_prep_w<<<prep_grid, 256, 0, stream>>>(W3, Wt3);

    // ---- layer 1 (fp32 input, cast fused) ----
    k_gemm<true><<<gemm_grid, 256, 0, stream>>>(x, Wt1, dinv, hs);
    k_gather_bf<<<gath_grid, 256, 0, stream>>>(hs, rs, csr, dinv, scale1, shift1, xbuf);
    // ---- layer 2 ----
    k_gemm<false><<<gemm_grid, 256, 0, stream>>>(xbuf, Wt2, dinv, hs);
    k_gather_bf<<<gath_grid, 256, 0, stream>>>(hs, rs, csr, dinv, scale2, shift2, xbuf);
    // ---- layer 3 ----
    k_gemm<false><<<gemm_grid, 256, 0, stream>>>(xbuf, Wt3, dinv, hs);
    k_gather_bf<<<gath_grid, 256, 0, stream>>>(hs, rs, csr, dinv, scale3, shift3, xbuf);

    // ---- pool + final ----
    k_pool_final2<<<NG, 256, 0, stream>>>(xbuf, gstart, Wl, bl, out);
}

// Round 6
// 508.125 us; speedup vs baseline: 1.1024x; 1.1024x over previous
//
#include <hip/hip_runtime.h>
#include <hip/hip_bf16.h>

// Problem constants (match reference)
#define NN 100000     // nodes
#define NE 1600000    // edges
#define HD 128        // feature/hidden dim
#define NG 512        // graphs
#define BN_EPS 1e-5f

#define GEMM_BLOCKS 1563          // ceil(NN/64)
#define HIST_BLOCKS 6250          // NE/256

typedef __attribute__((ext_vector_type(8))) short short8;
typedef __attribute__((ext_vector_type(4))) float floatx4;

// ---- bf16 helpers (RNE) ----
__device__ __forceinline__ ushort f2bf(float f) {
    union { float f; uint u; } v; v.f = f;
    uint r = (v.u + 0x7FFF + ((v.u >> 16) & 1)) >> 16;
    return (ushort)r;
}
__device__ __forceinline__ float bflo(uint u) { union { uint u; float f; } v; v.u = u << 16; return v.f; }
__device__ __forceinline__ float bfhi(uint u) { union { uint u; float f; } v; v.u = u & 0xFFFF0000u; return v.f; }

// ---------------- zero helper ----------------
__global__ void k_zero_i(int* p, int n) {
    int i = blockIdx.x * 256 + threadIdx.x;
    if (i < n) p[i] = 0;
}

// ---------------- W prep: Wt[n][k] = bf16(W[k][n]), 3 layers in one launch ----------------
__global__ void k_prep_w3(const float* __restrict__ W1, const float* __restrict__ W2,
                          const float* __restrict__ W3,
                          ushort* __restrict__ Wt1, ushort* __restrict__ Wt2,
                          ushort* __restrict__ Wt3) {
    int w = blockIdx.x >> 6;                       // 64 blocks per layer
    int i = (blockIdx.x & 63) * 256 + threadIdx.x; // 0..16383
    const float* W = (w == 0) ? W1 : (w == 1) ? W2 : W3;
    ushort* Wt = (w == 0) ? Wt1 : (w == 1) ? Wt2 : Wt3;
    int k = i >> 7, n = i & 127;
    Wt[n * 128 + k] = f2bf(W[i]);
}

// ---------------- fused: GEMM1 (fp32 x @ Wt1 -> unscaled bf16 hs)  ||  hist+rank ----------------
__launch_bounds__(256)
__global__ void k_fused1(const float* __restrict__ x, const ushort* __restrict__ Wt,
                         ushort* __restrict__ hs,
                         const int* __restrict__ dst, int* __restrict__ indeg,
                         int* __restrict__ rank) {
    const int tid = threadIdx.x;
    if (blockIdx.x >= GEMM_BLOCKS) {
        // ---- histogram + per-edge rank (one atomic pass) ----
        int e = (blockIdx.x - GEMM_BLOCKS) * 256 + tid;
        if (e < NE) rank[e] = atomicAdd(&indeg[dst[e]], 1);
        return;
    }
    // ---- GEMM role: 4 waves, 64 rows, B-frags straight from global (L1-resident 32 KB) ----
    const int wave = tid >> 6, lane = tid & 63;
    const int m = lane & 15, kg = lane >> 4;
    const long row0 = (long)blockIdx.x * 64 + wave * 16;

    long arow = row0 + m;
    long arc = arow < NN ? arow : (NN - 1);
    const float* xf = x + arc * 128;
    short8 a[4];
#pragma unroll
    for (int s = 0; s < 4; ++s) {
        float4 f0 = *(const float4*)(xf + s * 32 + kg * 8);
        float4 f1 = *(const float4*)(xf + s * 32 + kg * 8 + 4);
        short8 t;
        t[0] = (short)f2bf(f0.x); t[1] = (short)f2bf(f0.y);
        t[2] = (short)f2bf(f0.z); t[3] = (short)f2bf(f0.w);
        t[4] = (short)f2bf(f1.x); t[5] = (short)f2bf(f1.y);
        t[6] = (short)f2bf(f1.z); t[7] = (short)f2bf(f1.w);
        a[s] = t;
    }

    floatx4 acc[8];
#pragma unroll
    for (int ct = 0; ct < 8; ++ct) acc[ct] = (floatx4){0.f, 0.f, 0.f, 0.f};

#pragma unroll
    for (int s = 0; s < 4; ++s) {
#pragma unroll
        for (int ct = 0; ct < 8; ++ct) {
            short8 b = *(const short8*)(Wt + (ct * 16 + m) * 128 + s * 32 + kg * 8);
            acc[ct] = __builtin_amdgcn_mfma_f32_16x16x32_bf16(a[s], b, acc[ct], 0, 0, 0);
        }
    }

#pragma unroll
    for (int r = 0; r < 4; ++r) {
        long orow = row0 + kg * 4 + r;
        if (orow < NN) {
#pragma unroll
            for (int ct = 0; ct < 8; ++ct)
                hs[orow * 128 + ct * 16 + m] = f2bf(acc[ct][r]);   // unscaled
        }
    }
}

// ---------------- scan1 + dinv fused ----------------
__global__ void k_scan1d(const int* __restrict__ indeg, int* __restrict__ rs,
                         int* __restrict__ aux, float* __restrict__ dinv) {
    __shared__ int s[256];
    int t = threadIdx.x;
    int base = blockIdx.x * 1024 + t * 4;
    int v0 = 0, v1 = 0, v2 = 0, v3 = 0;
    if (base + 0 < NN) v0 = indeg[base + 0];
    if (base + 1 < NN) v1 = indeg[base + 1];
    if (base + 2 < NN) v2 = indeg[base + 2];
    if (base + 3 < NN) v3 = indeg[base + 3];
    if (base + 0 < NN) dinv[base + 0] = rsqrtf((float)(v0 + 1));
    if (base + 1 < NN) dinv[base + 1] = rsqrtf((float)(v1 + 1));
    if (base + 2 < NN) dinv[base + 2] = rsqrtf((float)(v2 + 1));
    if (base + 3 < NN) dinv[base + 3] = rsqrtf((float)(v3 + 1));
    int tsum = v0 + v1 + v2 + v3;
    s[t] = tsum;
    __syncthreads();
    for (int o = 1; o < 256; o <<= 1) {
        int x = 0;
        if (t >= o) x = s[t - o];
        __syncthreads();
        s[t] += x;
        __syncthreads();
    }
    int excl = s[t] - tsum;
    if (base + 0 < NN) rs[base + 0] = excl;
    if (base + 1 < NN) rs[base + 1] = excl + v0;
    if (base + 2 < NN) rs[base + 2] = excl + v0 + v1;
    if (base + 3 < NN) rs[base + 3] = excl + v0 + v1 + v2;
    if (t == 255) aux[blockIdx.x] = s[255];
}

__global__ void k_scan2(int* __restrict__ aux, int nblk) {
    __shared__ int s[128];
    int t = threadIdx.x;
    int v = (t < nblk) ? aux[t] : 0;
    s[t] = v;
    __syncthreads();
    for (int o = 1; o < 128; o <<= 1) {
        int x = 0;
        if (t >= o) x = s[t - o];
        __syncthreads();
        s[t] += x;
        __syncthreads();
    }
    if (t < nblk) aux[t] = s[t] - v;
}

__global__ void k_scan3(int* __restrict__ rs, const int* __restrict__ aux) {
    int i = blockIdx.x * 256 + threadIdx.x;
    if (i < NN) rs[i] += aux[i >> 10];
    if (i == 0) rs[NN] = NE;
}

// ---------------- CSR fill (atomic-free) ----------------
__global__ void k_fill(const int* __restrict__ src, const int* __restrict__ dst,
                       const int* __restrict__ rank, const int* __restrict__ rs,
                       int* __restrict__ csr) {
    int e = blockIdx.x * 256 + threadIdx.x;
    if (e >= NE) return;
    csr[rs[dst[e]] + rank[e]] = src[e];
}

// ---------------- BN affine prep: 3 layers in one launch ----------------
__global__ void k_bn_prep3(const float* __restrict__ b1, const float* __restrict__ g1,
                           const float* __restrict__ be1, const float* __restrict__ m1,
                           const float* __restrict__ v1,
                           const float* __restrict__ b2, const float* __restrict__ g2,
                           const float* __restrict__ be2, const float* __restrict__ m2,
                           const float* __restrict__ v2,
                           const float* __restrict__ b3, const float* __restrict__ g3,
                           const float* __restrict__ be3, const float* __restrict__ m3,
                           const float* __restrict__ v3,
                           float* scale1, float* shift1, float* scale2, float* shift2,
                           float* scale3, float* shift3) {
    int l = blockIdx.x, f = threadIdx.x;
    const float *b, *g, *be, *m, *v;
    float *sc, *sh;
    if (l == 0)      { b = b1; g = g1; be = be1; m = m1; v = v1; sc = scale1; sh = shift1; }
    else if (l == 1) { b = b2; g = g2; be = be2; m = m2; v = v2; sc = scale2; sh = shift2; }
    else             { b = b3; g = g3; be = be3; m = m3; v = v3; sc = scale3; sh = shift3; }
    float s = g[f] * rsqrtf(v[f] + BN_EPS);
    sc[f] = s;
    sh[f] = (b[f] - m[f]) * s + be[f];
}

// ---------------- graph boundaries ----------------
__global__ void k_gstart(const int* __restrict__ batch, int* __restrict__ gstart) {
    int g = blockIdx.x * 256 + threadIdx.x;
    if (g > NG) return;
    if (g == NG) { gstart[NG] = NN; return; }
    int lo = 0, hi = NN;
    while (lo < hi) {
        int mid = (lo + hi) >> 1;
        if (batch[mid] < g) lo = mid + 1; else hi = mid;
    }
    gstart[g] = lo;
}

// ---------------- MFMA GEMM layers 2/3 (R4-proven: LDS-staged W, scaled epilogue) ----------------
#define WT_STRIDE 136
__launch_bounds__(256)
__global__ void k_gemm_l23(const ushort* __restrict__ xb, const ushort* __restrict__ Wt,
                           const float* __restrict__ dinv, ushort* __restrict__ hs) {
    __shared__ ushort sWt[128 * WT_STRIDE];
    const int tid = threadIdx.x;
    // pure bf16 copy (Wt pre-transposed): 2048 uint4
    for (int i = tid; i < 2048; i += 256) {
        int row = i >> 4, seg = i & 15;
        *(uint4*)&sWt[row * WT_STRIDE + seg * 8] = *(const uint4*)(Wt + row * 128 + seg * 8);
    }
    __syncthreads();

    const int wave = tid >> 6, lane = tid & 63;
    const int m = lane & 15, kg = lane >> 4;
    const long row0 = (long)blockIdx.x * 64 + wave * 16;

    long arow = row0 + m;
    long arc = arow < NN ? arow : (NN - 1);
    short8 a[4];
#pragma unroll
    for (int s = 0; s < 4; ++s)
        a[s] = *(const short8*)(xb + arc * 128 + s * 32 + kg * 8);

    floatx4 acc[8];
#pragma unroll
    for (int ct = 0; ct < 8; ++ct) acc[ct] = (floatx4){0.f, 0.f, 0.f, 0.f};

#pragma unroll
    for (int s = 0; s < 4; ++s) {
#pragma unroll
        for (int ct = 0; ct < 8; ++ct) {
            short8 b = *(const short8*)&sWt[(ct * 16 + m) * WT_STRIDE + s * 32 + kg * 8];
            acc[ct] = __builtin_amdgcn_mfma_f32_16x16x32_bf16(a[s], b, acc[ct], 0, 0, 0);
        }
    }

#pragma unroll
    for (int r = 0; r < 4; ++r) {
        long orow = row0 + kg * 4 + r;
        if (orow < NN) {
            float dd = dinv[orow];
#pragma unroll
            for (int ct = 0; ct < 8; ++ct)
                hs[orow * 128 + ct * 16 + m] = f2bf(acc[ct][r] * dd);
        }
    }
}

// ---------------- gather + BN + ReLU fused (R4-proven 2x unroll) ----------------
// SCALE_SRC: hs rows are unscaled -> apply dinv[s] per edge, dinv[d] for self term (layer 1).
template <bool SCALE_SRC>
__global__ void k_gather_bf(const ushort* __restrict__ hs, const int* __restrict__ rs,
                            const int* __restrict__ csr, const float* __restrict__ dinv,
                            const float* __restrict__ scale, const float* __restrict__ shift,
                            ushort* __restrict__ xout) {
    int t = blockIdx.x * 256 + threadIdx.x;
    int d = t >> 4;
    if (d >= NN) return;
    int lane = t & 15;
    int c0 = lane * 8;
    int e0 = rs[d], e1 = rs[d + 1];
    float dd = dinv[d];

    uint4 sv = *(const uint4*)(hs + (long)d * 128 + c0);   // self-loop term
    float w = SCALE_SRC ? dd : 1.0f;
    float a0 = w * bflo(sv.x), a1 = w * bfhi(sv.x), a2 = w * bflo(sv.y), a3 = w * bfhi(sv.y);
    float a4 = w * bflo(sv.z), a5 = w * bfhi(sv.z), a6 = w * bflo(sv.w), a7 = w * bfhi(sv.w);

    int j = e0;
    for (; j + 1 < e1; j += 2) {
        int s0 = csr[j], s1 = csr[j + 1];
        uint4 v0 = *(const uint4*)(hs + (long)s0 * 128 + c0);
        uint4 v1 = *(const uint4*)(hs + (long)s1 * 128 + c0);
        if (SCALE_SRC) {
            float w0 = dinv[s0], w1 = dinv[s1];
            a0 += w0 * bflo(v0.x) + w1 * bflo(v1.x);
            a1 += w0 * bfhi(v0.x) + w1 * bfhi(v1.x);
            a2 += w0 * bflo(v0.y) + w1 * bflo(v1.y);
            a3 += w0 * bfhi(v0.y) + w1 * bfhi(v1.y);
            a4 += w0 * bflo(v0.z) + w1 * bflo(v1.z);
            a5 += w0 * bfhi(v0.z) + w1 * bfhi(v1.z);
            a6 += w0 * bflo(v0.w) + w1 * bflo(v1.w);
            a7 += w0 * bfhi(v0.w) + w1 * bfhi(v1.w);
        } else {
            a0 += bflo(v0.x) + bflo(v1.x); a1 += bfhi(v0.x) + bfhi(v1.x);
            a2 += bflo(v0.y) + bflo(v1.y); a3 += bfhi(v0.y) + bfhi(v1.y);
            a4 += bflo(v0.z) + bflo(v1.z); a5 += bfhi(v0.z) + bfhi(v1.z);
            a6 += bflo(v0.w) + bflo(v1.w); a7 += bfhi(v0.w) + bfhi(v1.w);
        }
    }
    if (j < e1) {
        int s0 = csr[j];
        uint4 v0 = *(const uint4*)(hs + (long)s0 * 128 + c0);
        float w0 = SCALE_SRC ? dinv[s0] : 1.0f;
        a0 += w0 * bflo(v0.x); a1 += w0 * bfhi(v0.x);
        a2 += w0 * bflo(v0.y); a3 += w0 * bfhi(v0.y);
        a4 += w0 * bflo(v0.z); a5 += w0 * bfhi(v0.z);
        a6 += w0 * bflo(v0.w); a7 += w0 * bfhi(v0.w);
    }

    float4 sca = *(const float4*)(scale + c0);
    float4 scb = *(const float4*)(scale + c0 + 4);
    float4 sha = *(const float4*)(shift + c0);
    float4 shb = *(const float4*)(shift + c0 + 4);
    float r0 = fmaxf(dd * a0 * sca.x + sha.x, 0.f);
    float r1 = fmaxf(dd * a1 * sca.y + sha.y, 0.f);
    float r2 = fmaxf(dd * a2 * sca.z + sha.z, 0.f);
    float r3 = fmaxf(dd * a3 * sca.w + sha.w, 0.f);
    float r4 = fmaxf(dd * a4 * scb.x + shb.x, 0.f);
    float r5 = fmaxf(dd * a5 * scb.y + shb.y, 0.f);
    float r6 = fmaxf(dd * a6 * scb.z + shb.z, 0.f);
    float r7 = fmaxf(dd * a7 * scb.w + shb.w, 0.f);
    uint4 o;
    o.x = (uint)f2bf(r0) | ((uint)f2bf(r1) << 16);
    o.y = (uint)f2bf(r2) | ((uint)f2bf(r3) << 16);
    o.z = (uint)f2bf(r4) | ((uint)f2bf(r5) << 16);
    o.w = (uint)f2bf(r6) | ((uint)f2bf(r7) << 16);
    *(uint4*)(xout + (long)d * 128 + c0) = o;
}

// ---------------- fused mean-pool + final linear ----------------
__global__ void k_pool_final2(const ushort* __restrict__ x, const int* __restrict__ gstart,
                              const float* __restrict__ Wl, const float* __restrict__ bl,
                              float* __restrict__ out) {
    __shared__ float red[256];
    int g = blockIdx.x;
    int tid = threadIdx.x;
    int f = tid & 127;
    int half = tid >> 7;
    int i0 = gstart[g], i1 = gstart[g + 1];

    float acc = 0.f;
    for (int i = i0 + half; i < i1; i += 2) {
        union { uint u; float f; } v; v.u = (uint)x[(long)i * 128 + f] << 16;
        acc += v.f;
    }
    red[tid] = acc;
    __syncthreads();
    if (tid < 128) red[tid] = (red[tid] + red[tid + 128]) * Wl[tid];
    __syncthreads();
    for (int o = 64; o > 0; o >>= 1) {
        if (tid < o) red[tid] += red[tid + o];
        __syncthreads();
    }
    if (tid == 0) out[g] = red[0] / fmaxf((float)(i1 - i0), 1.f) + bl[0];
}

// ---------------- launch ----------------
extern "C" void kernel_launch(void* const* d_in, const int* in_sizes, int n_in,
                              void* d_out, int out_size, void* d_ws, size_t ws_size,
                              hipStream_t stream) {
    const float* x   = (const float*)d_in[0];
    const int*   ei  = (const int*)d_in[1];
    const int*   bat = (const int*)d_in[2];
    const float* W1  = (const float*)d_in[3];
    const float* b1  = (const float*)d_in[4];
    const float* g1  = (const float*)d_in[5];
    const float* be1 = (const float*)d_in[6];
    const float* m1  = (const float*)d_in[7];
    const float* v1  = (const float*)d_in[8];
    const float* W2  = (const float*)d_in[9];
    const float* b2  = (const float*)d_in[10];
    const float* g2  = (const float*)d_in[11];
    const float* be2 = (const float*)d_in[12];
    const float* m2  = (const float*)d_in[13];
    const float* v2  = (const float*)d_in[14];
    const float* W3  = (const float*)d_in[15];
    const float* b3  = (const float*)d_in[16];
    const float* g3  = (const float*)d_in[17];
    const float* be3 = (const float*)d_in[18];
    const float* m3  = (const float*)d_in[19];
    const float* v3  = (const float*)d_in[20];
    const float* Wl  = (const float*)d_in[21];
    const float* bl  = (const float*)d_in[22];
    float* out = (float*)d_out;

    const int* srcp = ei;        // edge_index[0]
    const int* dstp = ei + NE;   // edge_index[1]

    // ---- workspace layout ----
    char* ws = (char*)d_ws;
    size_t off = 0;
    auto alloc = [&](size_t bytes) { char* p = ws + off; off += (bytes + 255) & ~255ULL; return p; };
    float*  dinv   = (float*) alloc(NN * 4);
    int*    indeg  = (int*)   alloc(NN * 4);
    int*    rs     = (int*)   alloc((NN + 1) * 4);
    int*    aux    = (int*)   alloc(128 * 4);
    int*    csr    = (int*)   alloc(NE * 4);           // 6.4 MB
    int*    rank   = (int*)   alloc(NE * 4);           // 6.4 MB
    float*  scale1 = (float*) alloc(HD * 4);
    float*  shift1 = (float*) alloc(HD * 4);
    float*  scale2 = (float*) alloc(HD * 4);
    float*  shift2 = (float*) alloc(HD * 4);
    float*  scale3 = (float*) alloc(HD * 4);
    float*  shift3 = (float*) alloc(HD * 4);
    int*    gstart = (int*)   alloc((NG + 1) * 4);
    ushort* Wt1    = (ushort*)alloc(128 * 128 * 2);    // 32 KB
    ushort* Wt2    = (ushort*)alloc(128 * 128 * 2);
    ushort* Wt3    = (ushort*)alloc(128 * 128 * 2);
    ushort* hs     = (ushort*)alloc((size_t)NN * HD * 2);   // 25.6 MB
    ushort* xbuf   = (ushort*)alloc((size_t)NN * HD * 2);   // 25.6 MB

    const int nblk_scan = (NN + 1023) / 1024;   // 98
    const int grid_n    = (NN + 255) / 256;
    const int grid_e    = (NE + 255) / 256;     // 6250
    const int gath_grid = (NN * 16 + 255) / 256;

    // ---- prep (independent of edges) ----
    k_zero_i<<<grid_n, 256, 0, stream>>>(indeg, NN);
    k_prep_w3<<<192, 256, 0, stream>>>(W1, W2, W3, Wt1, Wt2, Wt3);

    // ---- fused: GEMM1 (unscaled) || hist+rank ----
    k_fused1<<<GEMM_BLOCKS + HIST_BLOCKS, 256, 0, stream>>>(x, Wt1, hs, dstp, indeg, rank);

    // ---- CSR: scan (+dinv), fill ----
    k_scan1d<<<nblk_scan, 256, 0, stream>>>(indeg, rs, aux, dinv);
    k_scan2<<<1, 128, 0, stream>>>(aux, nblk_scan);
    k_scan3<<<grid_n, 256, 0, stream>>>(rs, aux);
    k_fill<<<grid_e, 256, 0, stream>>>(srcp, dstp, rank, rs, csr);

    // ---- BN prep + graph boundaries ----
    k_bn_prep3<<<3, 128, 0, stream>>>(b1, g1, be1, m1, v1, b2, g2, be2, m2, v2,
                                      b3, g3, be3, m3, v3,
                                      scale1, shift1, scale2, shift2, scale3, shift3);
    k_gstart<<<3, 256, 0, stream>>>(bat, gstart);

    // ---- layer 1 gather (applies dinv[s] and dinv[d]) ----
    k_gather_bf<true><<<gath_grid, 256, 0, stream>>>(hs, rs, csr, dinv, scale1, shift1, xbuf);
    // ---- layer 2 ----
    k_gemm_l23<<<GEMM_BLOCKS, 256, 0, stream>>>(xbuf, Wt2, dinv, hs);
    k_gather_bf<false><<<gath_grid, 256, 0, stream>>>(hs, rs, csr, dinv, scale2, shift2, xbuf);
    // ---- layer 3 ----
    k_gemm_l23<<<GEMM_BLOCKS, 256, 0, stream>>>(xbuf, Wt3, dinv, hs);
    k_gather_bf<false><<<gath_grid, 256, 0, stream>>>(hs, rs, csr, dinv, scale3, shift3, xbuf);

    // ---- pool + final ----
    k_pool_final2<<<NG, 256, 0, stream>>>(xbuf, gstart, Wl, bl, out);
}